// Round 11
// baseline (175.363 us; speedup 1.0000x reference)
//
#include <hip/hip_runtime.h>
#include <hip/hip_bf16.h>
#include <math.h>

#define NN 20000
#define DEGV 16
#define CINV 128
#define TSTEPS 3
#define HIDV 128

typedef float f32x4 __attribute__((ext_vector_type(4)));
typedef short s16x8 __attribute__((ext_vector_type(8)));

#define MFMA16(a, b, c) __builtin_amdgcn_mfma_f32_16x16x32_bf16(a, b, c, 0, 0, 0)

static __device__ __forceinline__ short f2bf(float x) {
    __hip_bfloat16 h = __float2bfloat16(x);
    return *reinterpret_cast<short*>(&h);
}

// ---------------------------------------------------------------------------
// Kernel 1: P[s][n][j] = sum_k v[n][k] * W1[(s*128+k)*64 + j]   (slot-major)
// 32 nodes/block (grid 625). Thread tile: 8 nl x 4 j registers.
// vt reads are float4 with XOR-quad swizzle (conflict-free, 4x fewer LDS ops).
// Per-thread FMA order identical to r9/r10 -> selection math bit-identical.
// ---------------------------------------------------------------------------
__global__ __launch_bounds__(256) void k_precompute(
    const float* __restrict__ v, const float* __restrict__ W1,
    const float* __restrict__ b1,
    float* __restrict__ P, float* __restrict__ base, int* __restrict__ walk_idx,
    short* __restrict__ vb)
{
    __shared__ float vt[32][132];   // row stride 132 floats (16B aligned); quads XOR-swizzled
    int nb = blockIdx.x * 32;
    for (int idx = threadIdx.x; idx < 32 * 128; idx += 256) {
        int nl = idx >> 7, k = idx & 127;
        float x = v[(size_t)(nb + nl) * 128 + k];
        int k4 = (k >> 2) ^ (nl >> 3);          // nl>>3 in 0..3, XORs low bits of quad idx
        vt[nl][(k4 << 2) | (k & 3)] = x;
        vb[(size_t)(nb + nl) * 128 + k] = f2bf(x);
    }
    __syncthreads();

    int s  = threadIdx.x >> 6;
    int jg = (threadIdx.x >> 2) & 15;
    int ng = threadIdx.x & 3;

    double accd[8][4];
#pragma unroll
    for (int i = 0; i < 8; ++i)
#pragma unroll
        for (int m = 0; m < 4; ++m) accd[i][m] = 0.0;

    const float* w1s = W1 + (size_t)s * 128 * 64 + jg;

    for (int kb = 0; kb < 8; ++kb) {
        float acc[8][4];
#pragma unroll
        for (int i = 0; i < 8; ++i)
#pragma unroll
            for (int m = 0; m < 4; ++m) acc[i][m] = 0.f;
#pragma unroll
        for (int kq = 0; kq < 4; ++kq) {
            int K4 = kb * 4 + kq;
            float4 xv[8];
#pragma unroll
            for (int i = 0; i < 8; ++i)
                xv[i] = *(const float4*)&vt[ng * 8 + i][(K4 ^ ng) << 2];
#pragma unroll
            for (int kk = 0; kk < 4; ++kk) {
                int k = K4 * 4 + kk;
                float w0 = w1s[k * 64 +  0];
                float w1 = w1s[k * 64 + 16];
                float w2 = w1s[k * 64 + 32];
                float w3 = w1s[k * 64 + 48];
#pragma unroll
                for (int i = 0; i < 8; ++i) {
                    float x = (kk == 0) ? xv[i].x : (kk == 1) ? xv[i].y
                            : (kk == 2) ? xv[i].z : xv[i].w;
                    acc[i][0] = fmaf(x, w0, acc[i][0]);
                    acc[i][1] = fmaf(x, w1, acc[i][1]);
                    acc[i][2] = fmaf(x, w2, acc[i][2]);
                    acc[i][3] = fmaf(x, w3, acc[i][3]);
                }
            }
        }
#pragma unroll
        for (int i = 0; i < 8; ++i)
#pragma unroll
            for (int m = 0; m < 4; ++m) accd[i][m] += (double)acc[i][m];
    }

#pragma unroll
    for (int i = 0; i < 8; ++i) {
        int n = nb + ng * 8 + i;
#pragma unroll
        for (int m = 0; m < 4; ++m) {
            int j = jg + 16 * m;
            float pv = (float)accd[i][m];
            P[(size_t)s * NN * 64 + (size_t)n * 64 + j] = pv;
            if (s == 0) {
                base[(size_t)n * 64 + j] = pv + b1[j];
                if (j == 0) walk_idx[n] = n;
            }
        }
    }
}

// ---------------------------------------------------------------------------
// Kernel 2: one walk selection step. One 64-lane wave per node. (unchanged —
// double math has matched numpy's f32 selections on this dataset 7/7 runs)
// ---------------------------------------------------------------------------
__global__ __launch_bounds__(256) void k_walk_step(
    const float* __restrict__ P, float* __restrict__ base,
    const int* __restrict__ dst, const float* __restrict__ W2,
    const float* __restrict__ b2, const float* __restrict__ noise,
    int* __restrict__ walk_idx, int t)
{
    int wave = threadIdx.x >> 6;
    int lane = threadIdx.x & 63;
    int n = blockIdx.x * 4 + wave;
    if (n >= NN) return;

    int wl = walk_idx[t * NN + n];
    int d = lane >> 2, sub = lane & 3;
    int cand = dst[wl * DEGV + d];

    const float* Pslice = P + (size_t)(t + 1) * NN * 64;
    const float4* b4 = (const float4*)(base + (size_t)n * 64);
    const float4* p4 = (const float4*)(Pslice + (size_t)cand * 64);
    const float4* w4 = (const float4*)W2;

    double acc = 0.0;
#pragma unroll
    for (int k = 0; k < 4; ++k) {
        float4 bb = b4[sub * 4 + k];
        float4 pp = p4[sub * 4 + k];
        float4 ww = w4[sub * 4 + k];
        acc += (double)fmaxf(bb.x + pp.x, 0.f) * (double)ww.x;
        acc += (double)fmaxf(bb.y + pp.y, 0.f) * (double)ww.y;
        acc += (double)fmaxf(bb.z + pp.z, 0.f) * (double)ww.z;
        acc += (double)fmaxf(bb.w + pp.w, 0.f) * (double)ww.w;
    }
    acc += __shfl_xor(acc, 1);
    acc += __shfl_xor(acc, 2);
    double logp = acc + (double)b2[0];

    double m = logp;
    for (int mask = 4; mask < 64; mask <<= 1) m = fmax(m, __shfl_xor(m, mask));
    double e = exp(logp - m);
    double ssum = e;
    for (int mask = 4; mask < 64; mask <<= 1) ssum += __shfl_xor(ssum, mask);
    double norm = m + log(ssum);

    double wp = exp(logp - norm) +
                0.01 * (double)noise[((size_t)t * NN + n) * DEGV + d];

    int bd = d;
    double bwp = wp;
    for (int mask = 4; mask < 64; mask <<= 1) {
        double owp = __shfl_xor(bwp, mask);
        int od = __shfl_xor(bd, mask);
        if (owp > bwp || (owp == bwp && od < bd)) { bwp = owp; bd = od; }
    }
    int sel = dst[wl * DEGV + bd];

    base[(size_t)n * 64 + lane] += Pslice[(size_t)sel * 64 + lane];
    if (lane == 0) walk_idx[(t + 1) * NN + n] = sel;
}

// ---------------------------------------------------------------------------
// Kernel 3: convert weights to bf16 (Wih, Whh row-major; Wout transposed)
// ---------------------------------------------------------------------------
__global__ __launch_bounds__(256) void k_convert_w(
    const float* __restrict__ Wih, const float* __restrict__ Whh,
    const float* __restrict__ Wout,
    short* __restrict__ Wihb, short* __restrict__ Whhb, short* __restrict__ WoutTb)
{
    int idx = blockIdx.x * 256 + threadIdx.x;
    if (idx < 49152) {
        Wihb[idx] = f2bf(Wih[idx]);
    } else if (idx < 98304) {
        int e = idx - 49152;
        Whhb[e] = f2bf(Whh[e]);
    } else if (idx < 114688) {
        int e = idx - 98304;
        int o = e >> 7, k = e & 127;
        WoutTb[e] = f2bf(Wout[k * 128 + o]);   // WoutT[o][k]
    }
}

// ---------------------------------------------------------------------------
// Kernel 4: fused GRU (4 steps) + output projection, MFMA bf16.
// v3: Block = 512 thr (8 waves), 16 NODES/block, grid 1250 (4.88 blocks/CU,
// tail loss 2.4%). Wave j owns u-slice j. SINGLE-PASS gates: aR/aZ/aIN/aHN
// accumulated together -> each x/h fragment LDS-read ONCE per step (16 vs 32
// wave-reads) and no sigmoid splitting the MFMA stream. Weights in regs,
// x double-buffered with register prefetch. 2 barriers/step.
// A-frag: row=lane&15, k=(lane>>4)*8 per K=32 chunk.
// C/D layout (verified): row=(lane>>4)*4+reg, col=lane&15.
// ---------------------------------------------------------------------------
__global__ __launch_bounds__(512, 2) void k_gru_fused(
    const short* __restrict__ vb, const int* __restrict__ widx,
    const short* __restrict__ Wihb, const short* __restrict__ Whhb,
    const short* __restrict__ WoutTb,
    const float* __restrict__ bih, const float* __restrict__ bhh,
    const float* __restrict__ bout, float* __restrict__ out)
{
    __shared__ short x_bf[2][16][136];
    __shared__ short h_bf[16][136];
    int tid = threadIdx.x;
    int j = tid >> 6, lane = tid & 63;      // wave j = u-slice j (0..7)
    int c = lane & 15, q = lane >> 4;
    int nb = blockIdx.x * 16;
    int u = j * 16 + c;

    float b_r  = bih[u] + bhh[u];
    float b_z  = bih[128 + u] + bhh[128 + u];
    float b_in = bih[256 + u];
    float b_hn = bhh[256 + u];

    const short* bi_base = Wihb   + c * 128 + q * 8 + j * 2048;
    const short* bh_base = Whhb   + c * 128 + q * 8 + j * 2048;
    const short* bo_base = WoutTb + c * 128 + q * 8 + j * 2048;

    // preload all B fragments (28 x s16x8)
    s16x8 wiR[4], wiZ[4], wiN[4], whR[4], whZ[4], whN[4], wo[4];
#pragma unroll
    for (int ks = 0; ks < 4; ++ks) {
        wiR[ks] = *(const s16x8*)(bi_base + ks * 32);
        wiZ[ks] = *(const s16x8*)(bi_base + 8 * 2048 + ks * 32);
        wiN[ks] = *(const s16x8*)(bi_base + 16 * 2048 + ks * 32);
        whR[ks] = *(const s16x8*)(bh_base + ks * 32);
        whZ[ks] = *(const s16x8*)(bh_base + 8 * 2048 + ks * 32);
        whN[ks] = *(const s16x8*)(bh_base + 16 * 2048 + ks * 32);
        wo[ks]  = *(const s16x8*)(bo_base + ks * 32);
    }

    float h_reg[4];
#pragma unroll
    for (int i = 0; i < 4; ++i) h_reg[i] = 0.f;

    int srow = tid >> 4, schunk = tid & 15;   // 32 rows x 16 chunks; rows >=16 idle
    bool stager = srow < 16;

    // stage x for t=0
    if (stager) {
        int src = widx[nb + srow];
        *(s16x8*)&x_bf[0][srow][schunk * 8] =
            *(const s16x8*)(vb + (size_t)src * 128 + schunk * 8);
    }
    __syncthreads();

#pragma unroll 1
    for (int t = 0; t < 1 + TSTEPS; ++t) {
        int cur = t & 1;

        // prefetch next step's x into a register
        s16x8 pref;
        if (t < TSTEPS && stager) {
            int src = widx[(t + 1) * NN + nb + srow];
            pref = *(const s16x8*)(vb + (size_t)src * 128 + schunk * 8);
        }

        // A-fragments read ONCE per step
        s16x8 ax[4], ah[4];
#pragma unroll
        for (int ks = 0; ks < 4; ++ks)
            ax[ks] = *(const s16x8*)&x_bf[cur][c][ks * 32 + q * 8];
        if (t > 0) {
#pragma unroll
            for (int ks = 0; ks < 4; ++ks)
                ah[ks] = *(const s16x8*)&h_bf[c][ks * 32 + q * 8];
        }

        f32x4 zf = {0.f, 0.f, 0.f, 0.f};
        f32x4 aR = zf, aZ = zf, aIN = zf, aHN = zf;
#pragma unroll
        for (int ks = 0; ks < 4; ++ks) {
            aR  = MFMA16(ax[ks], wiR[ks], aR);
            aZ  = MFMA16(ax[ks], wiZ[ks], aZ);
            aIN = MFMA16(ax[ks], wiN[ks], aIN);
        }
        if (t > 0) {
#pragma unroll
            for (int ks = 0; ks < 4; ++ks) {
                aR  = MFMA16(ah[ks], whR[ks], aR);
                aZ  = MFMA16(ah[ks], whZ[ks], aZ);
                aHN = MFMA16(ah[ks], whN[ks], aHN);
            }
        }

        __syncthreads();   // all x_bf[cur]/h_bf reads complete
        if (t < TSTEPS && stager)
            *(s16x8*)&x_bf[cur ^ 1][srow][schunk * 8] = pref;

#pragma unroll
        for (int i = 0; i < 4; ++i) {
            float r = 1.f / (1.f + __expf(-(aR[i] + b_r)));
            float z = 1.f / (1.f + __expf(-(aZ[i] + b_z)));
            float hnarg = (t > 0) ? (aHN[i] + b_hn) : b_hn;
            float narg = aIN[i] + b_in + r * hnarg;
            float e2 = __expf(2.f * narg);
            float ngt = 1.f - 2.f / (e2 + 1.f);    // tanh
            float hn = (1.f - z) * ngt + z * h_reg[i];
            h_reg[i] = hn;
            h_bf[q * 4 + i][u] = f2bf(hn);
        }
        __syncthreads();
    }

    // output projection: wave j handles o-tile j
    {
        s16x8 ah2[4];
#pragma unroll
        for (int ks = 0; ks < 4; ++ks)
            ah2[ks] = *(const s16x8*)&h_bf[c][ks * 32 + q * 8];
        f32x4 acco = {0.f, 0.f, 0.f, 0.f};
#pragma unroll
        for (int ks = 0; ks < 4; ++ks)
            acco = MFMA16(ah2[ks], wo[ks], acco);
        float bb = bout[u];
#pragma unroll
        for (int i = 0; i < 4; ++i)
            out[(size_t)(nb + q * 4 + i) * 128 + u] = acco[i] + bb;
    }
}

// ---------------------------------------------------------------------------
extern "C" void kernel_launch(void* const* d_in, const int* in_sizes, int n_in,
                              void* d_out, int out_size, void* d_ws, size_t ws_size,
                              hipStream_t stream)
{
    const float* node_attr = (const float*)d_in[0];
    const int*   edge_index = (const int*)d_in[1];
    const float* W1  = (const float*)d_in[3];
    const float* b1  = (const float*)d_in[4];
    const float* W2  = (const float*)d_in[5];
    const float* b2  = (const float*)d_in[6];
    const float* Wih = (const float*)d_in[7];
    const float* Whh = (const float*)d_in[8];
    const float* bih = (const float*)d_in[9];
    const float* bhh = (const float*)d_in[10];
    const float* Wout = (const float*)d_in[11];
    const float* bout = (const float*)d_in[12];
    const float* noise = (const float*)d_in[13];

    const int* dst = edge_index + (size_t)NN * DEGV;

    char* ws = (char*)d_ws;
    size_t offP    = 0;                               // 4*N*64 f32 = 20.48 MB
    size_t offBase = offP + (size_t)4 * NN * 64 * 4;  // N*64 f32   =  5.12 MB
    size_t offW    = offBase + (size_t)NN * 64 * 4;   // bf16 weights 0.23 MB
    size_t offWidx = offW + (size_t)(2 * 49152 + 16384) * 2;
    size_t offVb   = offWidx + (size_t)4 * NN * 4;    // bf16 v = 5.12 MB
    float* P    = (float*)(ws + offP);
    float* base = (float*)(ws + offBase);
    short* Wihb   = (short*)(ws + offW);
    short* Whhb   = Wihb + 384 * 128;
    short* WoutTb = Whhb + 384 * 128;
    int*   widx = (int*)(ws + offWidx);
    short* vb   = (short*)(ws + offVb);

    dim3 blk(256);
    k_convert_w<<<dim3(448), blk, 0, stream>>>(Wih, Whh, Wout, Wihb, Whhb, WoutTb);
    k_precompute<<<dim3(625), blk, 0, stream>>>(node_attr, W1, b1, P, base, widx, vb);
    for (int t = 0; t < TSTEPS; ++t)
        k_walk_step<<<dim3(5000), blk, 0, stream>>>(P, base, dst, W2, b2, noise, widx, t);
    k_gru_fused<<<dim3(1250), dim3(512), 0, stream>>>(vb, widx, Wihb, Whhb, WoutTb,
                                                      bih, bhh, bout, (float*)d_out);
}

// Round 12
// 156.242 us; speedup vs baseline: 1.1224x; 1.1224x over previous
//
#include <hip/hip_runtime.h>
#include <hip/hip_bf16.h>
#include <math.h>

#define NN 20000
#define DEGV 16
#define CINV 128
#define TSTEPS 3
#define HIDV 128

typedef float f32x4 __attribute__((ext_vector_type(4)));
typedef short s16x8 __attribute__((ext_vector_type(8)));

#define MFMA16(a, b, c) __builtin_amdgcn_mfma_f32_16x16x32_bf16(a, b, c, 0, 0, 0)

static __device__ __forceinline__ short f2bf(float x) {
    __hip_bfloat16 h = __float2bfloat16(x);
    return *reinterpret_cast<short*>(&h);
}

// fast f64 exp for x <= 0 (rel err ~1e-13): range-reduce + deg-12 Taylor + bit-scale
static __device__ __forceinline__ double exp_fast(double x) {
    const double LOG2E = 1.4426950408889634074;
    const double LN2HI = 6.93147180369123816490e-01;
    const double LN2LO = 1.90821492927058770002e-10;
    double fn = floor(fma(x, LOG2E, 0.5));
    double r  = fma(fn, -LN2HI, x);
    r = fma(fn, -LN2LO, r);
    double p = 2.08767569878680989792e-09;       // 1/12!
    p = fma(p, r, 2.50521083854417187751e-08);   // 1/11!
    p = fma(p, r, 2.75573192239858906526e-07);   // 1/10!
    p = fma(p, r, 2.75573192239858925110e-06);   // 1/9!
    p = fma(p, r, 2.48015873015873015873e-05);   // 1/8!
    p = fma(p, r, 1.98412698412698412526e-04);   // 1/7!
    p = fma(p, r, 1.38888888888888894568e-03);   // 1/6!
    p = fma(p, r, 8.33333333333333321769e-03);   // 1/5!
    p = fma(p, r, 4.16666666666666643537e-02);   // 1/4!
    p = fma(p, r, 1.66666666666666657415e-01);   // 1/3!
    p = fma(p, r, 5.0e-01);                      // 1/2!
    p = fma(p, r, 1.0);                          // (e^r - 1)/r
    p = fma(p, r, 1.0);                          // e^r
    long long bits = __double_as_longlong(p) + ((long long)(int)fn << 52);
    return __longlong_as_double(bits);
}

// ---------------------------------------------------------------------------
// Kernel 1: P[s][n][j] = sum_k v[n][k] * W1[(s*128+k)*64 + j]   (slot-major)
// 32 nodes/block (grid 625). Thread tile: 8 nl x 4 j. float4 LDS reads with
// XOR-quad swizzle. Per-thread FMA order identical to r9-r11.
// Emits vb (bf16 v), base, walk_idx[0].
// ---------------------------------------------------------------------------
__global__ __launch_bounds__(256) void k_precompute(
    const float* __restrict__ v, const float* __restrict__ W1,
    const float* __restrict__ b1,
    float* __restrict__ P, float* __restrict__ base, int* __restrict__ walk_idx,
    short* __restrict__ vb)
{
    __shared__ float vt[32][132];
    int nb = blockIdx.x * 32;
    for (int idx = threadIdx.x; idx < 32 * 128; idx += 256) {
        int nl = idx >> 7, k = idx & 127;
        float x = v[(size_t)(nb + nl) * 128 + k];
        int k4 = (k >> 2) ^ (nl >> 3);
        vt[nl][(k4 << 2) | (k & 3)] = x;
        vb[(size_t)(nb + nl) * 128 + k] = f2bf(x);
    }
    __syncthreads();

    int s  = threadIdx.x >> 6;
    int jg = (threadIdx.x >> 2) & 15;
    int ng = threadIdx.x & 3;

    double accd[8][4];
#pragma unroll
    for (int i = 0; i < 8; ++i)
#pragma unroll
        for (int m = 0; m < 4; ++m) accd[i][m] = 0.0;

    const float* w1s = W1 + (size_t)s * 128 * 64 + jg;

    for (int kb = 0; kb < 8; ++kb) {
        float acc[8][4];
#pragma unroll
        for (int i = 0; i < 8; ++i)
#pragma unroll
            for (int m = 0; m < 4; ++m) acc[i][m] = 0.f;
#pragma unroll
        for (int kq = 0; kq < 4; ++kq) {
            int K4 = kb * 4 + kq;
            float4 xv[8];
#pragma unroll
            for (int i = 0; i < 8; ++i)
                xv[i] = *(const float4*)&vt[ng * 8 + i][(K4 ^ ng) << 2];
#pragma unroll
            for (int kk = 0; kk < 4; ++kk) {
                int k = K4 * 4 + kk;
                float w0 = w1s[k * 64 +  0];
                float w1 = w1s[k * 64 + 16];
                float w2 = w1s[k * 64 + 32];
                float w3 = w1s[k * 64 + 48];
#pragma unroll
                for (int i = 0; i < 8; ++i) {
                    float x = (kk == 0) ? xv[i].x : (kk == 1) ? xv[i].y
                            : (kk == 2) ? xv[i].z : xv[i].w;
                    acc[i][0] = fmaf(x, w0, acc[i][0]);
                    acc[i][1] = fmaf(x, w1, acc[i][1]);
                    acc[i][2] = fmaf(x, w2, acc[i][2]);
                    acc[i][3] = fmaf(x, w3, acc[i][3]);
                }
            }
        }
#pragma unroll
        for (int i = 0; i < 8; ++i)
#pragma unroll
            for (int m = 0; m < 4; ++m) accd[i][m] += (double)acc[i][m];
    }

#pragma unroll
    for (int i = 0; i < 8; ++i) {
        int n = nb + ng * 8 + i;
#pragma unroll
        for (int m = 0; m < 4; ++m) {
            int j = jg + 16 * m;
            float pv = (float)accd[i][m];
            P[(size_t)s * NN * 64 + (size_t)n * 64 + j] = pv;
            if (s == 0) {
                base[(size_t)n * 64 + j] = pv + b1[j];
                if (j == 0) walk_idx[n] = n;
            }
        }
    }
}

// ---------------------------------------------------------------------------
// Kernel 2: ALL 3 walk steps fused, one wave per node (chains are per-node
// independent). base carried in registers (16 f32/lane, (d,sub) layout —
// identical values & FMA order to the split version). No LDS, no barriers.
// Softmax via e_d/sum (algebraically == exp(logp-norm)); exp = exp_fast
// (~1e-13 rel, decisions vs numpy unchanged).
// ---------------------------------------------------------------------------
__global__ __launch_bounds__(256) void k_walk_fused(
    const float* __restrict__ P, const float* __restrict__ base_g,
    const int* __restrict__ dst, const float* __restrict__ W2,
    const float* __restrict__ b2, const float* __restrict__ noise,
    int* __restrict__ walk_idx)
{
    int wave = threadIdx.x >> 6;
    int lane = threadIdx.x & 63;
    int n = blockIdx.x * 4 + wave;
    int d = lane >> 2, sub = lane & 3;

    float4 base_r[4], w2r[4];
    {
        const float4* bg = (const float4*)(base_g + (size_t)n * 64 + sub * 16);
        const float4* wg = ((const float4*)W2) + sub * 4;
#pragma unroll
        for (int k = 0; k < 4; ++k) { base_r[k] = bg[k]; w2r[k] = wg[k]; }
    }
    double b2d = (double)b2[0];

    int wl = n;
#pragma unroll 1
    for (int t = 0; t < TSTEPS; ++t) {
        const float* Pslice = P + (size_t)(t + 1) * NN * 64;
        int cand = dst[wl * DEGV + d];
        const float4* p4 = (const float4*)(Pslice + (size_t)cand * 64 + sub * 16);

        double acc = 0.0;
#pragma unroll
        for (int k = 0; k < 4; ++k) {
            float4 bb = base_r[k];
            float4 pp = p4[k];
            float4 ww = w2r[k];
            acc += (double)fmaxf(bb.x + pp.x, 0.f) * (double)ww.x;
            acc += (double)fmaxf(bb.y + pp.y, 0.f) * (double)ww.y;
            acc += (double)fmaxf(bb.z + pp.z, 0.f) * (double)ww.z;
            acc += (double)fmaxf(bb.w + pp.w, 0.f) * (double)ww.w;
        }
        acc += __shfl_xor(acc, 1);
        acc += __shfl_xor(acc, 2);
        double logp = acc + b2d;

        double m = logp;
        for (int mask = 4; mask < 64; mask <<= 1) m = fmax(m, __shfl_xor(m, mask));
        double e = exp_fast(logp - m);
        double ssum = e;
        for (int mask = 4; mask < 64; mask <<= 1) ssum += __shfl_xor(ssum, mask);

        double wp = e / ssum +
                    0.01 * (double)noise[((size_t)t * NN + n) * DEGV + d];

        int bd = d;
        double bwp = wp;
        for (int mask = 4; mask < 64; mask <<= 1) {
            double owp = __shfl_xor(bwp, mask);
            int od = __shfl_xor(bd, mask);
            if (owp > bwp || (owp == bwp && od < bd)) { bwp = owp; bd = od; }
        }
        int sel = dst[wl * DEGV + bd];

        const float4* ps = (const float4*)(Pslice + (size_t)sel * 64 + sub * 16);
#pragma unroll
        for (int k = 0; k < 4; ++k) {
            float4 pv = ps[k];
            base_r[k].x += pv.x; base_r[k].y += pv.y;
            base_r[k].z += pv.z; base_r[k].w += pv.w;
        }
        if (lane == 0) walk_idx[(t + 1) * NN + n] = sel;
        wl = sel;
    }
}

// ---------------------------------------------------------------------------
// Kernel 3: convert weights to bf16 (Wih, Whh row-major; Wout transposed)
// ---------------------------------------------------------------------------
__global__ __launch_bounds__(256) void k_convert_w(
    const float* __restrict__ Wih, const float* __restrict__ Whh,
    const float* __restrict__ Wout,
    short* __restrict__ Wihb, short* __restrict__ Whhb, short* __restrict__ WoutTb)
{
    int idx = blockIdx.x * 256 + threadIdx.x;
    if (idx < 49152) {
        Wihb[idx] = f2bf(Wih[idx]);
    } else if (idx < 98304) {
        int e = idx - 49152;
        Whhb[e] = f2bf(Whh[e]);
    } else if (idx < 114688) {
        int e = idx - 98304;
        int o = e >> 7, k = e & 127;
        WoutTb[e] = f2bf(Wout[k * 128 + o]);   // WoutT[o][k]
    }
}

// ---------------------------------------------------------------------------
// Kernel 4: fused GRU (4 steps) + output projection, MFMA bf16.
// EXACT round-9 version (best measured: 59.6 us, VGPR 64, no spill).
// Block = 512 thr (8 waves), 32 nodes. Grid 625. Wave j owns u-slice j;
// two-pass gates; weights from L2 per step; x gather = raw bf16 16B copy.
// ---------------------------------------------------------------------------
__global__ __launch_bounds__(512, 4) void k_gru_fused(
    const short* __restrict__ vb, const int* __restrict__ widx,
    const short* __restrict__ Wihb, const short* __restrict__ Whhb,
    const short* __restrict__ WoutTb,
    const float* __restrict__ bih, const float* __restrict__ bhh,
    const float* __restrict__ bout, float* __restrict__ out)
{
    __shared__ short x_bf[32][136];
    __shared__ short h_bf[32][136];
    int tid = threadIdx.x;
    int j = tid >> 6, lane = tid & 63;
    int c = lane & 15, q = lane >> 4;
    int nb = blockIdx.x * 32;
    int u = j * 16 + c;

    float b_r  = bih[u] + bhh[u];
    float b_z  = bih[128 + u] + bhh[128 + u];
    float b_in = bih[256 + u];
    float b_hn = bhh[256 + u];

    float h_reg[2][4];
#pragma unroll
    for (int g = 0; g < 2; ++g)
#pragma unroll
        for (int i = 0; i < 4; ++i) h_reg[g][i] = 0.f;

    const short* bi_base = Wihb + c * 128 + q * 8 + j * 2048;
    const short* bh_base = Whhb + c * 128 + q * 8 + j * 2048;

#pragma unroll 1
    for (int t = 0; t < 1 + TSTEPS; ++t) {
        {
            int row = tid >> 4, chunk = tid & 15;
            int src = widx[t * NN + nb + row];
            *(s16x8*)&x_bf[row][chunk * 8] =
                *(const s16x8*)(vb + (size_t)src * 128 + chunk * 8);
        }
        __syncthreads();

        float rr[2][4], zz[2][4];

        // pass 1: r and z
        {
            f32x4 zf = {0.f, 0.f, 0.f, 0.f};
            f32x4 aR[2] = {zf, zf}, aZ[2] = {zf, zf};
#pragma unroll
            for (int ks = 0; ks < 4; ++ks) {
                s16x8 biR = *(const s16x8*)(bi_base + ks * 32);
                s16x8 biZ = *(const s16x8*)(bi_base + 8 * 2048 + ks * 32);
#pragma unroll
                for (int g = 0; g < 2; ++g) {
                    s16x8 a = *(const s16x8*)&x_bf[g * 16 + c][ks * 32 + q * 8];
                    aR[g] = MFMA16(a, biR, aR[g]);
                    aZ[g] = MFMA16(a, biZ, aZ[g]);
                }
            }
            if (t > 0) {
#pragma unroll
                for (int ks = 0; ks < 4; ++ks) {
                    s16x8 bhR = *(const s16x8*)(bh_base + ks * 32);
                    s16x8 bhZ = *(const s16x8*)(bh_base + 8 * 2048 + ks * 32);
#pragma unroll
                    for (int g = 0; g < 2; ++g) {
                        s16x8 a = *(const s16x8*)&h_bf[g * 16 + c][ks * 32 + q * 8];
                        aR[g] = MFMA16(a, bhR, aR[g]);
                        aZ[g] = MFMA16(a, bhZ, aZ[g]);
                    }
                }
            }
#pragma unroll
            for (int g = 0; g < 2; ++g)
#pragma unroll
                for (int i = 0; i < 4; ++i) {
                    rr[g][i] = 1.f / (1.f + __expf(-(aR[g][i] + b_r)));
                    zz[g][i] = 1.f / (1.f + __expf(-(aZ[g][i] + b_z)));
                }
        }

        // pass 2: in and hn, then epilogue
        {
            f32x4 zf = {0.f, 0.f, 0.f, 0.f};
            f32x4 aIN[2] = {zf, zf}, aHN[2] = {zf, zf};
#pragma unroll
            for (int ks = 0; ks < 4; ++ks) {
                s16x8 biN = *(const s16x8*)(bi_base + 16 * 2048 + ks * 32);
#pragma unroll
                for (int g = 0; g < 2; ++g) {
                    s16x8 a = *(const s16x8*)&x_bf[g * 16 + c][ks * 32 + q * 8];
                    aIN[g] = MFMA16(a, biN, aIN[g]);
                }
            }
            if (t > 0) {
#pragma unroll
                for (int ks = 0; ks < 4; ++ks) {
                    s16x8 bhN = *(const s16x8*)(bh_base + 16 * 2048 + ks * 32);
#pragma unroll
                    for (int g = 0; g < 2; ++g) {
                        s16x8 a = *(const s16x8*)&h_bf[g * 16 + c][ks * 32 + q * 8];
                        aHN[g] = MFMA16(a, bhN, aHN[g]);
                    }
                }
            }
            __syncthreads();
#pragma unroll
            for (int g = 0; g < 2; ++g)
#pragma unroll
                for (int i = 0; i < 4; ++i) {
                    float narg = aIN[g][i] + b_in + rr[g][i] * (aHN[g][i] + b_hn);
                    float e2 = __expf(2.f * narg);
                    float ngt = 1.f - 2.f / (e2 + 1.f);
                    float hn = (1.f - zz[g][i]) * ngt + zz[g][i] * h_reg[g][i];
                    h_reg[g][i] = hn;
                    h_bf[g * 16 + q * 4 + i][u] = f2bf(hn);
                }
        }
        __syncthreads();
    }

    // output projection
    {
        const short* bo_base = WoutTb + c * 128 + q * 8 + j * 2048;
        f32x4 zf = {0.f, 0.f, 0.f, 0.f};
        f32x4 acco[2] = {zf, zf};
#pragma unroll
        for (int ks = 0; ks < 4; ++ks) {
            s16x8 bo = *(const s16x8*)(bo_base + ks * 32);
#pragma unroll
            for (int g = 0; g < 2; ++g) {
                s16x8 a = *(const s16x8*)&h_bf[g * 16 + c][ks * 32 + q * 8];
                acco[g] = MFMA16(a, bo, acco[g]);
            }
        }
        float bb = bout[u];
#pragma unroll
        for (int g = 0; g < 2; ++g)
#pragma unroll
            for (int i = 0; i < 4; ++i)
                out[(size_t)(nb + g * 16 + q * 4 + i) * 128 + u] = acco[g][i] + bb;
    }
}

// ---------------------------------------------------------------------------
extern "C" void kernel_launch(void* const* d_in, const int* in_sizes, int n_in,
                              void* d_out, int out_size, void* d_ws, size_t ws_size,
                              hipStream_t stream)
{
    const float* node_attr = (const float*)d_in[0];
    const int*   edge_index = (const int*)d_in[1];
    const float* W1  = (const float*)d_in[3];
    const float* b1  = (const float*)d_in[4];
    const float* W2  = (const float*)d_in[5];
    const float* b2  = (const float*)d_in[6];
    const float* Wih = (const float*)d_in[7];
    const float* Whh = (const float*)d_in[8];
    const float* bih = (const float*)d_in[9];
    const float* bhh = (const float*)d_in[10];
    const float* Wout = (const float*)d_in[11];
    const float* bout = (const float*)d_in[12];
    const float* noise = (const float*)d_in[13];

    const int* dst = edge_index + (size_t)NN * DEGV;

    char* ws = (char*)d_ws;
    size_t offP    = 0;                               // 4*N*64 f32 = 20.48 MB
    size_t offBase = offP + (size_t)4 * NN * 64 * 4;  // N*64 f32   =  5.12 MB
    size_t offW    = offBase + (size_t)NN * 64 * 4;   // bf16 weights 0.23 MB
    size_t offWidx = offW + (size_t)(2 * 49152 + 16384) * 2;
    size_t offVb   = offWidx + (size_t)4 * NN * 4;    // bf16 v = 5.12 MB
    float* P    = (float*)(ws + offP);
    float* base = (float*)(ws + offBase);
    short* Wihb   = (short*)(ws + offW);
    short* Whhb   = Wihb + 384 * 128;
    short* WoutTb = Whhb + 384 * 128;
    int*   widx = (int*)(ws + offWidx);
    short* vb   = (short*)(ws + offVb);

    dim3 blk(256);
    k_convert_w<<<dim3(448), blk, 0, stream>>>(Wih, Whh, Wout, Wihb, Whhb, WoutTb);
    k_precompute<<<dim3(625), blk, 0, stream>>>(node_attr, W1, b1, P, base, widx, vb);
    k_walk_fused<<<dim3(5000), blk, 0, stream>>>(P, base, dst, W2, b2, noise, widx);
    k_gru_fused<<<dim3(625), dim3(512), 0, stream>>>(vb, widx, Wihb, Whhb, WoutTb,
                                                     bih, bhh, bout, (float*)d_out);
}